// Round 5
// baseline (74.416 us; speedup 1.0000x reference)
//
#include <hip/hip_runtime.h>
#include <hip/hip_bf16.h>

// E=1024, H=16, P=64, B=2, S=2048. All f32 in/out.
// Pipeline (algebra verified rounds 1-4, absmax <= 0.5):
//   WpT[zp][i] = sum_j proj_w[j][p] * Wz[i][j]   (GEMM M=64p x N=1024i x K=1024, full-K)
//                -> bf16 hi/lo planes [192][1024]
//   Weff[p][e] = sum_h (h+1)*RW[h*64+p][e];  lam = exp(q1.k1)-exp(q2.k2)+lam0
//   q,k,v      = x @ Wp + bias   (full-K per block; q -> bf16 planes, k/v -> f32)
//   Mpart      = per-32-row-chunk k^T v;  Meff = 0.125*(c<32?1:-lam)*sum(Mpart)
//   G[b]       = Meff @ Weff -> GT bf16 planes [b][1024 e][64 c]
//   out[b]     = Q @ G via MFMA
// Split-bf16 MFMA: A*B ~= Ahi*Bhi + Ahi*Blo + Alo*Bhi (rel err ~1e-4).
// Reg-prefetch double-buffer: globals for chunk c+1 issued between barriers of
// chunk c (latency hides under MFMA phase); raw s_barrier closes the phase.

typedef __attribute__((ext_vector_type(8))) short short8;
typedef __attribute__((ext_vector_type(4))) float f32x4;
typedef unsigned short ushort_t;
typedef unsigned int uint_t;

__device__ inline ushort_t f2bf(float v) {
    uint_t u = __float_as_uint(v);
    return (ushort_t)((u + 0x7FFF + ((u >> 16) & 1)) >> 16);   // RNE
}
__device__ inline float bf2f(ushort_t h) { return __uint_as_float(((uint_t)h) << 16); }
__device__ inline void split2(float v, ushort_t& hi, ushort_t& lo) {
    hi = f2bf(v);
    lo = f2bf(v - bf2f(hi));
}
__device__ inline int swzA(int row, int k) { return (row * 64 + k) ^ ((row & 7) << 3); }

// ---- K1: WpT tiles (48 blocks) + Weff (64 blocks) + lam (1 block). grid 113.
__global__ __launch_bounds__(256) void prep2(
    const float* __restrict__ WQ, const float* __restrict__ WK, const float* __restrict__ WV,
    const float* __restrict__ proj_w, const float* __restrict__ RW,
    const float* __restrict__ q1v, const float* __restrict__ k1v,
    const float* __restrict__ q2v, const float* __restrict__ k2v,
    const float* __restrict__ lam0,
    ushort_t* __restrict__ WpThi, ushort_t* __restrict__ WpTlo,
    float* __restrict__ Weff, float* __restrict__ lamOut)
{
    int bid = blockIdx.x, tid = threadIdx.x;
    if (bid < 48) {
        __shared__ __align__(16) ushort_t Ah[4096], Al[4096], Bh[4096], Bl[4096];
        int z = bid >> 4, icb = bid & 15;
        const float* Wz = (z == 0) ? WQ : (z == 1) ? WK : WV;
        int i0 = icb * 64;
        int wave = tid >> 6, lane = tid & 63, rl = lane & 15, kg = lane >> 4;
        f32x4 acc[4] = {};
        float4 av[4], bv[4];
        #pragma unroll
        for (int i = 0; i < 4; ++i) {
            int pos = tid + 256 * i;
            int r = pos >> 4, c4 = (pos & 15) * 4;
            av[i] = *(const float4*)&proj_w[(long long)r * 64 + c4];       // A: j=r, p=c4..
            bv[i] = *(const float4*)&Wz[(long long)(i0 + r) * 1024 + c4];  // B: i=r, k=c4..
        }
        for (int ch = 0; ch < 16; ++ch) {
            #pragma unroll
            for (int i = 0; i < 4; ++i) {
                int pos = tid + 256 * i;
                int r = pos >> 4, c4 = (pos & 15) * 4;
                // A[p][j] = proj_w[j][p]: transpose-scatter (row=p=c4+j, k=r)
                float va[4] = {av[i].x, av[i].y, av[i].z, av[i].w};
                #pragma unroll
                for (int j = 0; j < 4; ++j) {
                    ushort_t h, l; split2(va[j], h, l);
                    int idx = swzA(c4 + j, r);
                    Ah[idx] = h; Al[idx] = l;
                }
                // Bt[i][j] = Wz[i0+i][j]: direct (row=i=r, k=c4..)
                ushort4 h4, l4;
                split2(bv[i].x, h4.x, l4.x); split2(bv[i].y, h4.y, l4.y);
                split2(bv[i].z, h4.z, l4.z); split2(bv[i].w, h4.w, l4.w);
                int bi = swzA(r, c4);
                *(ushort4*)&Bh[bi] = h4;
                *(ushort4*)&Bl[bi] = l4;
            }
            __syncthreads();
            if (ch < 15) {
                int k0 = (ch + 1) * 64;
                #pragma unroll
                for (int i = 0; i < 4; ++i) {
                    int pos = tid + 256 * i;
                    int r = pos >> 4, c4 = (pos & 15) * 4;
                    av[i] = *(const float4*)&proj_w[(long long)(k0 + r) * 64 + c4];
                    bv[i] = *(const float4*)&Wz[(long long)(i0 + r) * 1024 + k0 + c4];
                }
            }
            int ar = wave * 16 + rl;
            #pragma unroll
            for (int ks = 0; ks < 2; ++ks) {
                int kb = ks * 32 + kg * 8;
                short8 ah = *(const short8*)&Ah[swzA(ar, kb)];
                short8 al = *(const short8*)&Al[swzA(ar, kb)];
                #pragma unroll
                for (int n = 0; n < 4; ++n) {
                    int bi = swzA(n * 16 + rl, kb);
                    short8 bh = *(const short8*)&Bh[bi];
                    short8 bl = *(const short8*)&Bl[bi];
                    acc[n] = __builtin_amdgcn_mfma_f32_16x16x32_bf16(ah, bh, acc[n], 0, 0, 0);
                    acc[n] = __builtin_amdgcn_mfma_f32_16x16x32_bf16(ah, bl, acc[n], 0, 0, 0);
                    acc[n] = __builtin_amdgcn_mfma_f32_16x16x32_bf16(al, bh, acc[n], 0, 0, 0);
                }
            }
            __builtin_amdgcn_s_barrier();
        }
        // epilogue: WpT[z*64 + p][i0 + icol] split to planes
        #pragma unroll
        for (int n = 0; n < 4; ++n) {
            int icol = i0 + n * 16 + rl;
            #pragma unroll
            for (int j = 0; j < 4; ++j) {
                int prow = wave * 16 + kg * 4 + j;
                ushort_t h, l; split2(acc[n][j], h, l);
                long long idx = (long long)(z * 64 + prow) * 1024 + icol;
                WpThi[idx] = h; WpTlo[idx] = l;
            }
        }
    } else if (bid < 112) {
        int f4i = (bid - 48) * 256 + tid;   // 16384 f4 over Weff[64][1024]
        int p = f4i >> 8, e4 = (f4i & 255) * 4;
        float4 s = {0.f, 0.f, 0.f, 0.f};
        #pragma unroll
        for (int h = 0; h < 16; ++h) {
            float4 r = *(const float4*)&RW[(long long)(h * 64 + p) * 1024 + e4];
            float m = (float)(h + 1);
            s.x += m * r.x; s.y += m * r.y; s.z += m * r.z; s.w += m * r.w;
        }
        *(float4*)&Weff[(long long)p * 1024 + e4] = s;
    } else {
        __shared__ float red[2][4];
        float d1 = 0.f, d2 = 0.f;
        for (int i = tid; i < 1024; i += 256) {
            d1 += q1v[i] * k1v[i];
            d2 += q2v[i] * k2v[i];
        }
        #pragma unroll
        for (int off = 32; off > 0; off >>= 1) {
            d1 += __shfl_down(d1, off);
            d2 += __shfl_down(d2, off);
        }
        int wave = tid >> 6;
        if ((tid & 63) == 0) { red[0][wave] = d1; red[1][wave] = d2; }
        __syncthreads();
        if (tid == 0) {
            float s1 = red[0][0] + red[0][1] + red[0][2] + red[0][3];
            float s2 = red[1][0] + red[1][1] + red[1][2] + red[1][3];
            *lamOut = expf(s1) - expf(s2) + lam0[0];
        }
    }
}

// ---- K2: q,k,v full-K per block. grid 192 = z(3) x rowblk(64).
__global__ __launch_bounds__(256) void qkv2(
    const float* __restrict__ x,
    const ushort_t* __restrict__ WpThi, const ushort_t* __restrict__ WpTlo,
    const float* __restrict__ proj_b,
    ushort_t* __restrict__ Qhi, ushort_t* __restrict__ Qlo,
    float* __restrict__ kbuf, float* __restrict__ vbuf)
{
    __shared__ __align__(16) ushort_t Ah[4096], Al[4096], Bh[4096], Bl[4096];
    int bid = blockIdx.x, tid = threadIdx.x;
    int z = bid >> 6, rowblk = bid & 63;
    long long row0 = (long long)rowblk * 64;
    int wave = tid >> 6, lane = tid & 63, rl = lane & 15, kg = lane >> 4;
    f32x4 acc[4] = {};
    float4 av[4];
    short8 pbh[2], pbl[2];
    #pragma unroll
    for (int i = 0; i < 4; ++i) {
        int pos = tid + 256 * i;
        int r = pos >> 4, c4 = (pos & 15) * 4;
        av[i] = *(const float4*)&x[(row0 + r) * 1024 + c4];
    }
    #pragma unroll
    for (int i = 0; i < 2; ++i) {
        int pos = tid + 256 * i;
        int n = pos >> 3, k8 = (pos & 7) * 8;
        long long src = (long long)(z * 64 + n) * 1024 + k8;
        pbh[i] = *(const short8*)&WpThi[src];
        pbl[i] = *(const short8*)&WpTlo[src];
    }
    for (int ch = 0; ch < 16; ++ch) {
        #pragma unroll
        for (int i = 0; i < 4; ++i) {
            int pos = tid + 256 * i;
            int r = pos >> 4, c4 = (pos & 15) * 4;
            ushort4 h, l;
            split2(av[i].x, h.x, l.x); split2(av[i].y, h.y, l.y);
            split2(av[i].z, h.z, l.z); split2(av[i].w, h.w, l.w);
            int idx = swzA(r, c4);
            *(ushort4*)&Ah[idx] = h;
            *(ushort4*)&Al[idx] = l;
        }
        #pragma unroll
        for (int i = 0; i < 2; ++i) {
            int pos = tid + 256 * i;
            int n = pos >> 3, k8 = (pos & 7) * 8;
            int idx = swzA(n, k8);
            *(short8*)&Bh[idx] = pbh[i];
            *(short8*)&Bl[idx] = pbl[i];
        }
        __syncthreads();
        if (ch < 15) {
            int k0 = (ch + 1) * 64;
            #pragma unroll
            for (int i = 0; i < 4; ++i) {
                int pos = tid + 256 * i;
                int r = pos >> 4, c4 = (pos & 15) * 4;
                av[i] = *(const float4*)&x[(row0 + r) * 1024 + k0 + c4];
            }
            #pragma unroll
            for (int i = 0; i < 2; ++i) {
                int pos = tid + 256 * i;
                int n = pos >> 3, k8 = (pos & 7) * 8;
                long long src = (long long)(z * 64 + n) * 1024 + k0 + k8;
                pbh[i] = *(const short8*)&WpThi[src];
                pbl[i] = *(const short8*)&WpTlo[src];
            }
        }
        int ar = wave * 16 + rl;
        #pragma unroll
        for (int ks = 0; ks < 2; ++ks) {
            int kb = ks * 32 + kg * 8;
            short8 ah = *(const short8*)&Ah[swzA(ar, kb)];
            short8 al = *(const short8*)&Al[swzA(ar, kb)];
            #pragma unroll
            for (int n = 0; n < 4; ++n) {
                int bi = swzA(n * 16 + rl, kb);
                short8 bh = *(const short8*)&Bh[bi];
                short8 bl = *(const short8*)&Bl[bi];
                acc[n] = __builtin_amdgcn_mfma_f32_16x16x32_bf16(ah, bh, acc[n], 0, 0, 0);
                acc[n] = __builtin_amdgcn_mfma_f32_16x16x32_bf16(ah, bl, acc[n], 0, 0, 0);
                acc[n] = __builtin_amdgcn_mfma_f32_16x16x32_bf16(al, bh, acc[n], 0, 0, 0);
            }
        }
        __builtin_amdgcn_s_barrier();
    }
    #pragma unroll
    for (int n = 0; n < 4; ++n) {
        int col = n * 16 + rl;
        float bb = proj_b[col];
        #pragma unroll
        for (int j = 0; j < 4; ++j) {
            long long row = row0 + wave * 16 + kg * 4 + j;
            float val = acc[n][j] + bb;
            if (z == 0) {
                ushort_t h, l; split2(val, h, l);
                Qhi[row * 64 + col] = h;
                Qlo[row * 64 + col] = l;
            } else if (z == 1) {
                kbuf[row * 64 + col] = val;
            } else {
                vbuf[row * 64 + col] = val;
            }
        }
    }
}

// ---- K3: Mpart[b][sc][c][p] over 32-row chunks. grid 128 = sc(64) x b(2).
__global__ __launch_bounds__(256) void mpart2(
    const float* __restrict__ kbuf, const float* __restrict__ vbuf,
    float* __restrict__ Mpart)
{
    int bid = blockIdx.x;
    int sc = bid & 63, b = bid >> 6;
    __shared__ float ksh[32][68], vsh[32][68];
    int tid = threadIdx.x;
    long long row0 = (long long)b * 2048 + sc * 32;
    #pragma unroll
    for (int i = 0; i < 4; ++i) {
        int pos = tid + 256 * i;        // 1024: arr(2) x r(32) x c4(16)
        int arr = pos >> 9, rem = pos & 511;
        int r = rem >> 4, c4 = (rem & 15) * 4;
        const float* src = (arr ? vbuf : kbuf) + (row0 + r) * 64 + c4;
        float4 v = *(const float4*)src;
        if (arr == 0) *(float4*)&ksh[r][c4] = v;
        else          *(float4*)&vsh[r][c4] = v;
    }
    __syncthreads();
    int p = tid & 63, cg = tid >> 6;
    float acc[16] = {};
    for (int s = 0; s < 32; ++s) {
        float vv = vsh[s][p];
        float4 k0 = *(const float4*)&ksh[s][cg * 16];
        float4 k1 = *(const float4*)&ksh[s][cg * 16 + 4];
        float4 k2 = *(const float4*)&ksh[s][cg * 16 + 8];
        float4 k3 = *(const float4*)&ksh[s][cg * 16 + 12];
        acc[0] += k0.x * vv;  acc[1] += k0.y * vv;  acc[2] += k0.z * vv;  acc[3] += k0.w * vv;
        acc[4] += k1.x * vv;  acc[5] += k1.y * vv;  acc[6] += k1.z * vv;  acc[7] += k1.w * vv;
        acc[8] += k2.x * vv;  acc[9] += k2.y * vv;  acc[10] += k2.z * vv; acc[11] += k2.w * vv;
        acc[12] += k3.x * vv; acc[13] += k3.y * vv; acc[14] += k3.z * vv; acc[15] += k3.w * vv;
    }
    float* o = Mpart + ((long long)b * 64 + sc) * 4096;
    #pragma unroll
    for (int ci = 0; ci < 16; ++ci)
        o[(cg * 16 + ci) * 64 + p] = acc[ci];
}

// ---- K4: Meff = 0.125*(c<32?1:-lam)*sum_sc Mpart. grid 32.
__global__ __launch_bounds__(256) void meffk(
    const float* __restrict__ Mpart, const float* __restrict__ lamPtr,
    float* __restrict__ Meff)
{
    int idx = blockIdx.x * 256 + threadIdx.x;  // 8192
    int b = idx >> 12, cp = idx & 4095, c = cp >> 6;
    const float* base = Mpart + (long long)b * 262144 + cp;
    float s = 0.f;
    #pragma unroll 8
    for (int sc = 0; sc < 64; ++sc) s += base[(long long)sc * 4096];
    float lam = *lamPtr;
    Meff[idx] = s * 0.125f * (c < 32 ? 1.0f : -lam);
}

// ---- K5: G = Meff @ Weff -> GT planes [b][e][c]. grid 32 = colblk(16) x b(2).
__global__ __launch_bounds__(256) void gkern2(
    const float* __restrict__ Meff, const float* __restrict__ Weff,
    ushort_t* __restrict__ GThi, ushort_t* __restrict__ GTlo)
{
    int colblk = blockIdx.x & 15, b = blockIdx.x >> 4;
    __shared__ float As[64][68];
    __shared__ float Bs[64][68];
    int tid = threadIdx.x;
    #pragma unroll
    for (int i = 0; i < 4; ++i) {
        int pos = tid + 256 * i;        // 1024 f4 over Meff[64 c][64 p]
        int c = pos >> 4, p4 = (pos & 15) * 4;
        *(float4*)&As[c][p4] = *(const float4*)&Meff[(long long)b * 4096 + c * 64 + p4];
    }
    #pragma unroll
    for (int i = 0; i < 4; ++i) {
        int pos = tid + 256 * i;
        int kk = pos >> 4, n4 = (pos & 15) * 4;
        *(float4*)&Bs[kk][n4] = *(const float4*)&Weff[(long long)kk * 1024 + colblk * 64 + n4];
    }
    __syncthreads();

    int tx = tid & 15, ty = tid >> 4;
    float acc[4][4] = {};
    #pragma unroll 4
    for (int kk4 = 0; kk4 < 64; kk4 += 4) {
        float4 a4[4], b4[4];
        #pragma unroll
        for (int i = 0; i < 4; ++i) a4[i] = *(const float4*)&As[ty * 4 + i][kk4];
        #pragma unroll
        for (int r = 0; r < 4; ++r) b4[r] = *(const float4*)&Bs[kk4 + r][tx * 4];
        #pragma unroll
        for (int i = 0; i < 4; ++i) {
            acc[i][0] += a4[i].x * b4[0].x + a4[i].y * b4[1].x + a4[i].z * b4[2].x + a4[i].w * b4[3].x;
            acc[i][1] += a4[i].x * b4[0].y + a4[i].y * b4[1].y + a4[i].z * b4[2].y + a4[i].w * b4[3].y;
            acc[i][2] += a4[i].x * b4[0].z + a4[i].y * b4[1].z + a4[i].z * b4[2].z + a4[i].w * b4[3].z;
            acc[i][3] += a4[i].x * b4[0].w + a4[i].y * b4[1].w + a4[i].z * b4[2].w + a4[i].w * b4[3].w;
        }
    }
    #pragma unroll
    for (int i = 0; i < 4; ++i)
        #pragma unroll
        for (int j = 0; j < 4; ++j) {
            ushort_t h, l; split2(acc[i][j], h, l);
            long long idx = (long long)b * 65536 + (long long)(colblk * 64 + tx * 4 + j) * 64 + ty * 4 + i;
            GThi[idx] = h; GTlo[idx] = l;
        }
}

// ---- K6: out = Q @ G (plane loads + MFMA). grid 1024.
__global__ __launch_bounds__(256) void outk(
    const ushort_t* __restrict__ Qhi, const ushort_t* __restrict__ Qlo,
    const ushort_t* __restrict__ GThi, const ushort_t* __restrict__ GTlo,
    float* __restrict__ out)
{
    __shared__ __align__(16) ushort_t Ah[4096], Al[4096], Bh[4096], Bl[4096];
    int bid = blockIdx.x;
    int rowblk = bid & 31, colblk = (bid >> 5) & 15, b = bid >> 9;
    int tid = threadIdx.x;
    long long row0 = (long long)b * 2048 + rowblk * 64;

    #pragma unroll
    for (int i = 0; i < 2; ++i) {
        int pos = tid + 256 * i;
        int n = pos >> 3, k8 = (pos & 7) * 8;
        int idx = swzA(n, k8);
        long long qsrc = (row0 + n) * 64 + k8;
        long long gsrc = (long long)b * 65536 + (long long)(colblk * 64 + n) * 64 + k8;
        *(short8*)&Ah[idx] = *(const short8*)&Qhi[qsrc];
        *(short8*)&Al[idx] = *(const short8*)&Qlo[qsrc];
        *(short8*)&Bh[idx] = *(const short8*)&GThi[gsrc];
        *(short8*)&Bl[idx] = *(const short8*)&GTlo[gsrc];
    }
    __syncthreads();

    int wave = tid >> 6, lane = tid & 63;
    int rl = lane & 15, kg = lane >> 4;
    f32x4 acc[4] = {};
    int ar = wave * 16 + rl;
    #pragma unroll
    for (int ks = 0; ks < 2; ++ks) {
        int kb = ks * 32 + kg * 8;
        short8 ah = *(const short8*)&Ah[swzA(ar, kb)];
        short8 al = *(const short8*)&Al[swzA(ar, kb)];
        #pragma unroll
        for (int n = 0; n < 4; ++n) {
            int bi = swzA(n * 16 + rl, kb);
            short8 bh = *(const short8*)&Bh[bi];
            short8 bl = *(const short8*)&Bl[bi];
            acc[n] = __builtin_amdgcn_mfma_f32_16x16x32_bf16(ah, bh, acc[n], 0, 0, 0);
            acc[n] = __builtin_amdgcn_mfma_f32_16x16x32_bf16(ah, bl, acc[n], 0, 0, 0);
            acc[n] = __builtin_amdgcn_mfma_f32_16x16x32_bf16(al, bh, acc[n], 0, 0, 0);
        }
    }
    #pragma unroll
    for (int n = 0; n < 4; ++n) {
        int col = colblk * 64 + n * 16 + rl;
        #pragma unroll
        for (int j = 0; j < 4; ++j) {
            int row = rowblk * 64 + wave * 16 + kg * 4 + j;
            out[(long long)b * 2097152 + (long long)row * 1024 + col] = acc[n][j];
        }
    }
}

extern "C" void kernel_launch(void* const* d_in, const int* in_sizes, int n_in,
                              void* d_out, int out_size, void* d_ws, size_t ws_size,
                              hipStream_t stream)
{
    const float* x      = (const float*)d_in[0];
    const float* WQ     = (const float*)d_in[1];
    const float* WK     = (const float*)d_in[2];
    const float* WV     = (const float*)d_in[3];
    const float* RW     = (const float*)d_in[4];
    const float* proj_w = (const float*)d_in[5];
    const float* proj_b = (const float*)d_in[6];
    const float* q1v    = (const float*)d_in[7];
    const float* k1v    = (const float*)d_in[8];
    const float* q2v    = (const float*)d_in[9];
    const float* k2v    = (const float*)d_in[10];
    const float* lam0   = (const float*)d_in[11];
    float* out = (float*)d_out;

    float* ws    = (float*)d_ws;
    float* kbuf  = ws;                  // 262144
    float* vbuf  = ws + 262144;         // 262144
    float* Mpart = ws + 524288;         // 524288
    float* Weff  = ws + 1048576;        // 65536
    float* Meff  = ws + 1114112;        // 8192
    float* lam   = ws + 1122304;        // 16
    ushort_t* ub = (ushort_t*)(ws + 1122320);
    ushort_t* WpThi = ub;               // 196608
    ushort_t* WpTlo = ub + 196608;
    ushort_t* Qhi   = ub + 393216;      // 262144
    ushort_t* Qlo   = ub + 655360;
    ushort_t* GThi  = ub + 917504;      // 131072
    ushort_t* GTlo  = ub + 1048576;

    dim3 blk(256);
    prep2<<<dim3(113), blk, 0, stream>>>(WQ, WK, WV, proj_w, RW,
                                         q1v, k1v, q2v, k2v, lam0,
                                         WpThi, WpTlo, Weff, lam);
    qkv2<<<dim3(192), blk, 0, stream>>>(x, WpThi, WpTlo, proj_b, Qhi, Qlo, kbuf, vbuf);
    mpart2<<<dim3(128), blk, 0, stream>>>(kbuf, vbuf, Mpart);
    meffk<<<dim3(32), blk, 0, stream>>>(Mpart, lam, Meff);
    gkern2<<<dim3(32), blk, 0, stream>>>(Meff, Weff, GThi, GTlo);
    outk<<<dim3(1024), blk, 0, stream>>>(Qhi, Qlo, GThi, GTlo, out);
}